// Round 1
// baseline (602.026 us; speedup 1.0000x reference)
//
#include <hip/hip_runtime.h>
#include <stdint.h>

#define DMODEL 1024
#define NHEADS 16
#define HDIM   64
#define BB     4
#define SS     2048
#define MM     (BB*SS)            // 8192 rows
#define QKV_ELEMS ((size_t)BB*NHEADS*SS*HDIM)   // 8388608

typedef unsigned short ushort_t;
typedef __bf16 bf16x8 __attribute__((ext_vector_type(8)));
typedef float  floatx4 __attribute__((ext_vector_type(4)));

__device__ inline ushort_t f32_to_bf16(float f) {
    union { float f; uint32_t u; } v; v.f = f;
    uint32_t r = v.u + 0x7FFF + ((v.u >> 16) & 1);   // round-nearest-even
    return (ushort_t)(r >> 16);
}

// ---------------------------------------------------------------------------
// GEMM: C[m,n] = sum_k A[m,k] * W[n,k] + bias[n]   (Linear with W row-major)
// MODE 0: A fp32, output bf16 scattered to [B,H,S,HDIM] layout, scaled
// MODE 1: A bf16 (ushort), output fp32 row-major [M, DMODEL]
// Tile: 128x128, BK=32, 4 waves each computing 4x4 of 16x16 MFMA tiles.
// ---------------------------------------------------------------------------
template<int MODE>
__global__ __launch_bounds__(256) void gemm128(
    const void* __restrict__ Aptr, const float* __restrict__ W,
    const float* __restrict__ bias, void* __restrict__ Optr, float scale)
{
    constexpr int BK  = 32;
    constexpr int LDA = 40;   // 32 + 8 pad (80B rows: b128-aligned, <=2-way bank)
    __shared__ ushort_t As[128 * LDA];
    __shared__ ushort_t Bs[128 * LDA];

    const int tid  = threadIdx.x;
    const int lane = tid & 63;
    const int wid  = tid >> 6;
    const int quad = lane >> 4;
    const int l15  = lane & 15;
    const int m0   = blockIdx.y * 128;
    const int n0   = blockIdx.x * 128;
    const int wr   = wid >> 1, wc = wid & 1;

    floatx4 acc[4][4];
    #pragma unroll
    for (int i = 0; i < 4; i++)
        #pragma unroll
        for (int j = 0; j < 4; j++)
            acc[i][j] = (floatx4){0.f, 0.f, 0.f, 0.f};

    const int srow = tid >> 1;          // 0..127
    const int scol = (tid & 1) * 16;    // 0 or 16

    for (int k0 = 0; k0 < DMODEL; k0 += BK) {
        // ---- stage A tile ----
        if (MODE == 0) {
            const float* src = (const float*)Aptr + (size_t)(m0 + srow) * DMODEL + k0 + scol;
            ushort_t tmp[16];
            #pragma unroll
            for (int i = 0; i < 16; i++) tmp[i] = f32_to_bf16(src[i]);
            *(uint4*)&As[srow * LDA + scol]     = *(uint4*)&tmp[0];
            *(uint4*)&As[srow * LDA + scol + 8] = *(uint4*)&tmp[8];
        } else {
            const ushort_t* src = (const ushort_t*)Aptr + (size_t)(m0 + srow) * DMODEL + k0 + scol;
            *(uint4*)&As[srow * LDA + scol]     = *(const uint4*)&src[0];
            *(uint4*)&As[srow * LDA + scol + 8] = *(const uint4*)&src[8];
        }
        // ---- stage B tile (rows of W, fp32 -> bf16) ----
        {
            const float* src = W + (size_t)(n0 + srow) * DMODEL + k0 + scol;
            ushort_t tmp[16];
            #pragma unroll
            for (int i = 0; i < 16; i++) tmp[i] = f32_to_bf16(src[i]);
            *(uint4*)&Bs[srow * LDA + scol]     = *(uint4*)&tmp[0];
            *(uint4*)&Bs[srow * LDA + scol + 8] = *(uint4*)&tmp[8];
        }
        __syncthreads();

        bf16x8 af[4], bfr[4];
        #pragma unroll
        for (int i = 0; i < 4; i++)
            af[i]  = *(const bf16x8*)&As[(wr * 64 + i * 16 + l15) * LDA + quad * 8];
        #pragma unroll
        for (int j = 0; j < 4; j++)
            bfr[j] = *(const bf16x8*)&Bs[(wc * 64 + j * 16 + l15) * LDA + quad * 8];
        #pragma unroll
        for (int i = 0; i < 4; i++)
            #pragma unroll
            for (int j = 0; j < 4; j++)
                acc[i][j] = __builtin_amdgcn_mfma_f32_16x16x32_bf16(af[i], bfr[j], acc[i][j], 0, 0, 0);
        __syncthreads();
    }

    // ---- epilogue ----
    #pragma unroll
    for (int j = 0; j < 4; j++) {
        const int n = n0 + wc * 64 + j * 16 + l15;
        const float bn = bias[n];
        #pragma unroll
        for (int i = 0; i < 4; i++) {
            #pragma unroll
            for (int r = 0; r < 4; r++) {
                const int m = m0 + wr * 64 + i * 16 + quad * 4 + r;
                float v = (acc[i][j][r] + bn) * scale;
                if (MODE == 0) {
                    const int b = m >> 11, s = m & 2047;
                    const int h = n >> 6,  dh = n & 63;
                    ((ushort_t*)Optr)[(((size_t)(b * NHEADS + h)) * SS + s) * HDIM + dh] = f32_to_bf16(v);
                } else {
                    ((float*)Optr)[(size_t)m * DMODEL + n] = v;
                }
            }
        }
    }
}

// ---------------------------------------------------------------------------
// Flash attention: grid (S/64, B*H), block 256 (4 waves x 16 q-rows).
// KV tiles of 64 keys staged in LDS (V transposed). Softmax scale folded
// into Q at projection time. ctx written bf16 as [B,S,DMODEL].
// ---------------------------------------------------------------------------
__global__ __launch_bounds__(256) void attn_kernel(
    const ushort_t* __restrict__ Q, const ushort_t* __restrict__ K,
    const ushort_t* __restrict__ V, ushort_t* __restrict__ ctx)
{
    constexpr int LDK = 72;   // 64 + 8 pad (144B rows)
    __shared__ ushort_t Ks[64 * LDK];
    __shared__ ushort_t Vt[64 * LDK];
    __shared__ ushort_t Ps[4][16 * LDK];

    const int tid  = threadIdx.x;
    const int lane = tid & 63;
    const int wid  = tid >> 6;
    const int quad = lane >> 4;
    const int l15  = lane & 15;
    const int bh   = blockIdx.y;          // b*16 + h
    const int b    = bh >> 4, h = bh & 15;
    const int q0   = blockIdx.x * 64 + wid * 16;

    const ushort_t* Qb = Q + (size_t)bh * SS * HDIM;
    const ushort_t* Kb = K + (size_t)bh * SS * HDIM;
    const ushort_t* Vb = V + (size_t)bh * SS * HDIM;

    // Q fragments (A-operand), held for the whole kernel
    bf16x8 aq[2];
    #pragma unroll
    for (int c = 0; c < 2; c++)
        aq[c] = *(const bf16x8*)&Qb[(size_t)(q0 + l15) * HDIM + c * 32 + quad * 8];

    floatx4 acc[4];
    #pragma unroll
    for (int n = 0; n < 4; n++) acc[n] = (floatx4){0.f, 0.f, 0.f, 0.f};
    float mrow[4], lrow[4];
    #pragma unroll
    for (int r = 0; r < 4; r++) { mrow[r] = -1e30f; lrow[r] = 0.f; }

    const int srow = tid >> 2;          // 0..63 (key)
    const int scol = (tid & 3) * 16;    // dim chunk

    for (int kt = 0; kt < SS; kt += 64) {
        // ---- stage K tile and transposed V tile ----
        {
            const ushort_t* ksrc = Kb + (size_t)(kt + srow) * HDIM + scol;
            *(uint4*)&Ks[srow * LDK + scol]     = *(const uint4*)&ksrc[0];
            *(uint4*)&Ks[srow * LDK + scol + 8] = *(const uint4*)&ksrc[8];
            const ushort_t* vsrc = Vb + (size_t)(kt + srow) * HDIM + scol;
            ushort_t vv[16];
            *(uint4*)&vv[0] = *(const uint4*)&vsrc[0];
            *(uint4*)&vv[8] = *(const uint4*)&vsrc[8];
            #pragma unroll
            for (int i = 0; i < 16; i++) Vt[(scol + i) * LDK + srow] = vv[i];
        }
        __syncthreads();

        // ---- QK^T: 16 q-rows x 64 keys ----
        floatx4 s[4];
        #pragma unroll
        for (int nt = 0; nt < 4; nt++) {
            floatx4 cz = (floatx4){0.f, 0.f, 0.f, 0.f};
            bf16x8 k0f = *(const bf16x8*)&Ks[(nt * 16 + l15) * LDK + quad * 8];
            bf16x8 k1f = *(const bf16x8*)&Ks[(nt * 16 + l15) * LDK + 32 + quad * 8];
            cz = __builtin_amdgcn_mfma_f32_16x16x32_bf16(aq[0], k0f, cz, 0, 0, 0);
            cz = __builtin_amdgcn_mfma_f32_16x16x32_bf16(aq[1], k1f, cz, 0, 0, 0);
            s[nt] = cz;
        }

        // ---- online softmax (rows = quad*4+r, reduce across 16 lanes) ----
        float tmax[4];
        #pragma unroll
        for (int r = 0; r < 4; r++) {
            float v = fmaxf(fmaxf(s[0][r], s[1][r]), fmaxf(s[2][r], s[3][r]));
            #pragma unroll
            for (int off = 1; off < 16; off <<= 1) v = fmaxf(v, __shfl_xor(v, off));
            tmax[r] = v;
        }
        float mnew[4], alpha[4], psum[4];
        #pragma unroll
        for (int r = 0; r < 4; r++) {
            mnew[r]  = fmaxf(mrow[r], tmax[r]);
            alpha[r] = __expf(mrow[r] - mnew[r]);
            psum[r]  = 0.f;
        }
        #pragma unroll
        for (int nt = 0; nt < 4; nt++) {
            #pragma unroll
            for (int r = 0; r < 4; r++) {
                float p = __expf(s[nt][r] - mnew[r]);
                psum[r] += p;
                Ps[wid][(quad * 4 + r) * LDK + nt * 16 + l15] = f32_to_bf16(p);
            }
        }
        #pragma unroll
        for (int r = 0; r < 4; r++) {
            float v = psum[r];
            #pragma unroll
            for (int off = 1; off < 16; off <<= 1) v += __shfl_xor(v, off);
            lrow[r] = lrow[r] * alpha[r] + v;
            mrow[r] = mnew[r];
        }
        #pragma unroll
        for (int n = 0; n < 4; n++)
            #pragma unroll
            for (int r = 0; r < 4; r++)
                acc[n][r] *= alpha[r];

        // ---- PV: P (16x64, LDS round-trip) times V (64 keys x 64 dims) ----
        #pragma unroll
        for (int c = 0; c < 2; c++) {
            bf16x8 ap = *(const bf16x8*)&Ps[wid][l15 * LDK + c * 32 + quad * 8];
            #pragma unroll
            for (int n = 0; n < 4; n++) {
                bf16x8 vf = *(const bf16x8*)&Vt[(n * 16 + l15) * LDK + c * 32 + quad * 8];
                acc[n] = __builtin_amdgcn_mfma_f32_16x16x32_bf16(ap, vf, acc[n], 0, 0, 0);
            }
        }
        __syncthreads();
    }

    // ---- epilogue: normalize, write ctx [B,S,DMODEL] bf16 ----
    float inv[4];
    #pragma unroll
    for (int r = 0; r < 4; r++) inv[r] = 1.f / lrow[r];
    #pragma unroll
    for (int n = 0; n < 4; n++) {
        #pragma unroll
        for (int r = 0; r < 4; r++) {
            const int q = q0 + quad * 4 + r;
            const int d = h * HDIM + n * 16 + l15;
            ctx[((size_t)(b * SS + q)) * DMODEL + d] = f32_to_bf16(acc[n][r] * inv[r]);
        }
    }
}

extern "C" void kernel_launch(void* const* d_in, const int* in_sizes, int n_in,
                              void* d_out, int out_size, void* d_ws, size_t ws_size,
                              hipStream_t stream) {
    const float* query = (const float*)d_in[0];
    const float* key_  = (const float*)d_in[1];
    const float* value = (const float*)d_in[2];
    const float* Wq = (const float*)d_in[3];
    const float* bq = (const float*)d_in[4];
    const float* Wk = (const float*)d_in[5];
    const float* bk = (const float*)d_in[6];
    const float* Wv = (const float*)d_in[7];
    const float* bv = (const float*)d_in[8];
    const float* Wo = (const float*)d_in[9];
    const float* bo = (const float*)d_in[10];
    float* out = (float*)d_out;

    ushort_t* Qw = (ushort_t*)d_ws;          // [B,H,S,HDIM] bf16
    ushort_t* Kw = Qw + QKV_ELEMS;
    ushort_t* Vw = Kw + QKV_ELEMS;
    ushort_t* Cw = Vw + QKV_ELEMS;           // ctx [B,S,DMODEL] bf16

    dim3 blk(256);
    dim3 gp(DMODEL / 128, MM / 128);

    // softmax scale 1/sqrt(64) folded into Q projection
    hipLaunchKernelGGL((gemm128<0>), gp, blk, 0, stream, (const void*)query, Wq, bq, (void*)Qw, 0.125f);
    hipLaunchKernelGGL((gemm128<0>), gp, blk, 0, stream, (const void*)key_,  Wk, bk, (void*)Kw, 1.0f);
    hipLaunchKernelGGL((gemm128<0>), gp, blk, 0, stream, (const void*)value, Wv, bv, (void*)Vw, 1.0f);
    hipLaunchKernelGGL(attn_kernel, dim3(SS / 64, BB * NHEADS), blk, 0, stream, Qw, Kw, Vw, Cw);
    hipLaunchKernelGGL((gemm128<1>), gp, blk, 0, stream, (const void*)Cw, Wo, bo, (void*)out, 1.0f);
}

// Round 2
// 433.837 us; speedup vs baseline: 1.3877x; 1.3877x over previous
//
#include <hip/hip_runtime.h>
#include <stdint.h>

#define DMODEL 1024
#define NHEADS 16
#define HDIM   64
#define BB     4
#define SS     2048
#define MM     (BB*SS)                      // 8192 rows
#define QKV_ELEMS ((size_t)8388608)         // B*S*DMODEL

typedef unsigned short ushort_t;
typedef __bf16    bf16x8 __attribute__((ext_vector_type(8)));
typedef _Float16  half4  __attribute__((ext_vector_type(4)));
typedef float     floatx4 __attribute__((ext_vector_type(4)));

__device__ inline ushort_t f32_to_bf16(float f) {
    union { float f; uint32_t u; } v; v.f = f;
    uint32_t r = v.u + 0x7FFF + ((v.u >> 16) & 1);   // RNE
    return (ushort_t)(r >> 16);
}
__device__ inline ushort_t f32_to_f16u(float f) {
    union { _Float16 h; ushort_t u; } v; v.h = (_Float16)f; return v.u;
}
__device__ inline void glds16(const void* g, void* l) {
    __builtin_amdgcn_global_load_lds(
        (const __attribute__((address_space(1))) unsigned int*)g,
        (__attribute__((address_space(3))) unsigned int*)l, 16, 0, 0);
}

// ---------------------------------------------------------------------------
// fp32 -> bf16 elementwise convert; each block converts 2048 elements.
// ---------------------------------------------------------------------------
__global__ __launch_bounds__(256) void convert_bf16(const float* __restrict__ in,
                                                    ushort_t* __restrict__ out) {
    size_t i = ((size_t)blockIdx.x * 256 + threadIdx.x) * 8;
    float4 a = *(const float4*)&in[i];
    float4 b = *(const float4*)&in[i + 4];
    ushort_t t[8];
    t[0] = f32_to_bf16(a.x); t[1] = f32_to_bf16(a.y);
    t[2] = f32_to_bf16(a.z); t[3] = f32_to_bf16(a.w);
    t[4] = f32_to_bf16(b.x); t[5] = f32_to_bf16(b.y);
    t[6] = f32_to_bf16(b.z); t[7] = f32_to_bf16(b.w);
    *(uint4*)&out[i] = *(uint4*)t;
}

// three weight matrices in one launch (grid.y selects)
__global__ __launch_bounds__(256) void convert_w3(
    const float* __restrict__ w0, const float* __restrict__ w1, const float* __restrict__ w2,
    ushort_t* __restrict__ o0, ushort_t* __restrict__ o1, ushort_t* __restrict__ o2) {
    const float* src = (blockIdx.y == 0) ? w0 : (blockIdx.y == 1) ? w1 : w2;
    ushort_t*    dst = (blockIdx.y == 0) ? o0 : (blockIdx.y == 1) ? o1 : o2;
    size_t i = ((size_t)blockIdx.x * 256 + threadIdx.x) * 8;
    float4 a = *(const float4*)&src[i];
    float4 b = *(const float4*)&src[i + 4];
    ushort_t t[8];
    t[0] = f32_to_bf16(a.x); t[1] = f32_to_bf16(a.y);
    t[2] = f32_to_bf16(a.z); t[3] = f32_to_bf16(a.w);
    t[4] = f32_to_bf16(b.x); t[5] = f32_to_bf16(b.y);
    t[6] = f32_to_bf16(b.z); t[7] = f32_to_bf16(b.w);
    *(uint4*)&dst[i] = *(uint4*)t;
}

// ---------------------------------------------------------------------------
// bf16 GEMM (m97 structure): C[m,n] = sum_k A[m,k]*W[n,k] (+bias)*scale
// A: bf16 [M,1024] row-major, W: bf16 [1024,1024] row-major (Linear layout).
// 128x128 tile, BK=32, global_load_lds width=16, unpadded LDS.
// OUT: 0 = bf16 scatter to [B,H,S,HDIM]; 1 = f16 scatter; 2 = fp32 [M,DMODEL]
// ---------------------------------------------------------------------------
template<int OUT>
__global__ __launch_bounds__(256) void gemm_bf16(
    const ushort_t* __restrict__ A, const ushort_t* __restrict__ W,
    const float* __restrict__ bias, void* __restrict__ O, float scale)
{
    __shared__ ushort_t As[128 * 32];
    __shared__ ushort_t Bs[128 * 32];

    const int tid  = threadIdx.x;
    const int lane = tid & 63;
    const int quad = lane >> 4;
    const int l15  = lane & 15;
    const int wid  = tid >> 6;
    const int wr   = wid >> 1, wc = wid & 1;
    const int m0   = blockIdx.y * 128;
    const int n0   = blockIdx.x * 128;

    floatx4 acc[4][4];
    #pragma unroll
    for (int i = 0; i < 4; i++)
        #pragma unroll
        for (int j = 0; j < 4; j++)
            acc[i][j] = (floatx4){0.f, 0.f, 0.f, 0.f};

    for (int k0 = 0; k0 < DMODEL; k0 += 32) {
        #pragma unroll
        for (int j = 0; j < 2; j++) {
            const int p   = tid + j * 256;          // chunk 0..511
            const int row = p >> 2, cc = p & 3;     // 4x16B chunks per row
            glds16(&A[(size_t)(m0 + row) * DMODEL + k0 + cc * 8], &As[p * 8]);
            glds16(&W[(size_t)(n0 + row) * DMODEL + k0 + cc * 8], &Bs[p * 8]);
        }
        __syncthreads();

        bf16x8 af[4], bf[4];
        #pragma unroll
        for (int i = 0; i < 4; i++)
            af[i] = *(const bf16x8*)&As[(wr * 64 + i * 16 + l15) * 32 + quad * 8];
        #pragma unroll
        for (int j = 0; j < 4; j++)
            bf[j] = *(const bf16x8*)&Bs[(wc * 64 + j * 16 + l15) * 32 + quad * 8];
        #pragma unroll
        for (int i = 0; i < 4; i++)
            #pragma unroll
            for (int j = 0; j < 4; j++)
                acc[i][j] = __builtin_amdgcn_mfma_f32_16x16x32_bf16(af[i], bf[j], acc[i][j], 0, 0, 0);
        __syncthreads();
    }

    #pragma unroll
    for (int j = 0; j < 4; j++) {
        const int n = n0 + wc * 64 + j * 16 + l15;
        const float bn = bias[n];
        #pragma unroll
        for (int i = 0; i < 4; i++) {
            #pragma unroll
            for (int r = 0; r < 4; r++) {
                const int m = m0 + wr * 64 + i * 16 + quad * 4 + r;
                float v = (acc[i][j][r] + bn) * scale;
                if (OUT == 0) {
                    const int b = m >> 11, s = m & 2047;
                    const int h = n >> 6,  dh = n & 63;
                    ((ushort_t*)O)[(((size_t)(b * NHEADS + h)) * SS + s) * HDIM + dh] = f32_to_bf16(v);
                } else if (OUT == 1) {
                    const int b = m >> 11, s = m & 2047;
                    const int h = n >> 6,  dh = n & 63;
                    ((ushort_t*)O)[(((size_t)(b * NHEADS + h)) * SS + s) * HDIM + dh] = f32_to_f16u(v);
                } else {
                    ((float*)O)[(size_t)m * DMODEL + n] = v;
                }
            }
        }
    }
}

// ---------------------------------------------------------------------------
// Flash attention, transposed-score formulation.
// grid (S/128, B*H), block 256 = 4 waves x 32 q-rows.
// S^T = K·Q^T via 16x16x32 bf16 MFMA  -> C layout (row=key, col=q)
//   == B-operand layout of 16x16x16 MFMA, so exp(P) feeds PV directly
//   from registers (no LDS round-trip). PV: out^T = V^T · P^T, f16 MFMA.
// Q pre-scaled by 1/8 at projection. K bf16, V f16 in workspace.
// ---------------------------------------------------------------------------
__global__ __launch_bounds__(256) void attn_kernel(
    const ushort_t* __restrict__ Q, const ushort_t* __restrict__ K,
    const ushort_t* __restrict__ V, ushort_t* __restrict__ ctx)
{
    constexpr int LDV = 72;   // Vt row stride (ushorts): 2-way max on b32 writes
    __shared__ ushort_t smem[9216];
    ushort_t* Ks = smem;              // [64][64] bf16, chunk-XOR-swizzled rows
    ushort_t* Vt = smem + 4096;       // [64 d][LDV] f16 (transposed V)
    ushort_t* Tr = smem;              // epilogue: per-wave [32 q][LDV]

    const int tid  = threadIdx.x;
    const int lane = tid & 63;
    const int wid  = tid >> 6;
    const int quad = lane >> 4;
    const int l15  = lane & 15;
    const int bh   = blockIdx.y;
    const int b    = bh >> 4, h = bh & 15;
    const int q0   = blockIdx.x * 128 + wid * 32;

    const ushort_t* Qb = Q + (size_t)bh * SS * HDIM;
    const ushort_t* Kb = K + (size_t)bh * SS * HDIM;
    const ushort_t* Vb = V + (size_t)bh * SS * HDIM;

    // Q fragments (B-operand: lane&15 = q, quad*8+j = dim), 2 q-tiles
    bf16x8 qf[2][2];
    #pragma unroll
    for (int qt = 0; qt < 2; qt++)
        #pragma unroll
        for (int c = 0; c < 2; c++)
            qf[qt][c] = *(const bf16x8*)&Qb[(size_t)(q0 + qt * 16 + l15) * HDIM + c * 32 + quad * 8];

    floatx4 acc[2][4];
    #pragma unroll
    for (int qt = 0; qt < 2; qt++)
        #pragma unroll
        for (int dt = 0; dt < 4; dt++)
            acc[qt][dt] = (floatx4){0.f, 0.f, 0.f, 0.f};
    float mrun[2] = {-1e30f, -1e30f};
    float lrun[2] = {0.f, 0.f};

    // V-transpose staging assignment: key-pair kp = tid&31, d-chunk dc = tid>>5
    const int kp = tid & 31;
    const int dc = tid >> 5;

    for (int kt = 0; kt < SS; kt += 64) {
        // ---- stage K via global_load_lds (XOR swizzle on global chunk) ----
        #pragma unroll
        for (int j = 0; j < 2; j++) {
            const int p   = tid + j * 256;                // LDS chunk 0..511
            const int row = p >> 3;
            const int cc  = (p & 7) ^ (row & 7);          // global chunk
            glds16(&Kb[(size_t)(kt + row) * HDIM + cc * 8], &Ks[p * 8]);
        }
        // ---- stage V transposed: two keys per thread, b32 LDS writes ----
        {
            ushort_t ua[8], ub[8];
            *(uint4*)ua = *(const uint4*)&Vb[(size_t)(kt + 2 * kp) * HDIM + dc * 8];
            *(uint4*)ub = *(const uint4*)&Vb[(size_t)(kt + 2 * kp + 1) * HDIM + dc * 8];
            #pragma unroll
            for (int i = 0; i < 8; i++)
                *(uint32_t*)&Vt[(dc * 8 + i) * LDV + 2 * kp] = (uint32_t)ua[i] | ((uint32_t)ub[i] << 16);
        }
        __syncthreads();

        // ---- hoisted fragments (shared across both q-tiles) ----
        bf16x8 kf[4][2];
        #pragma unroll
        for (int nt = 0; nt < 4; nt++) {
            const int row = nt * 16 + l15;
            #pragma unroll
            for (int c = 0; c < 2; c++) {
                const int pos = (c * 4 + quad) ^ (row & 7);
                kf[nt][c] = *(const bf16x8*)&Ks[row * 64 + pos * 8];
            }
        }
        half4 vf[4][4];
        #pragma unroll
        for (int kb = 0; kb < 4; kb++)
            #pragma unroll
            for (int dt = 0; dt < 4; dt++)
                vf[kb][dt] = *(const half4*)&Vt[(dt * 16 + l15) * LDV + kb * 16 + quad * 4];

        #pragma unroll
        for (int qt = 0; qt < 2; qt++) {
            // S^T[key][q]: A=K (m=key), B=Q (n=q)
            floatx4 s[4];
            #pragma unroll
            for (int nt = 0; nt < 4; nt++) {
                floatx4 cz = (floatx4){0.f, 0.f, 0.f, 0.f};
                cz = __builtin_amdgcn_mfma_f32_16x16x32_bf16(kf[nt][0], qf[qt][0], cz, 0, 0, 0);
                cz = __builtin_amdgcn_mfma_f32_16x16x32_bf16(kf[nt][1], qf[qt][1], cz, 0, 0, 0);
                s[nt] = cz;
            }
            // online softmax: this lane's q = q0 + qt*16 + l15; reduce over
            // 16 in-register scores + 2 cross-quad shuffles
            float mx = s[0][0];
            #pragma unroll
            for (int nt = 0; nt < 4; nt++)
                #pragma unroll
                for (int r = 0; r < 4; r++) mx = fmaxf(mx, s[nt][r]);
            mx = fmaxf(mx, __shfl_xor(mx, 16));
            mx = fmaxf(mx, __shfl_xor(mx, 32));
            const float mnew  = fmaxf(mrun[qt], mx);
            const float alpha = __expf(mrun[qt] - mnew);
            mrun[qt] = mnew;

            float ps = 0.f;
            half4 pf[4];
            #pragma unroll
            for (int nt = 0; nt < 4; nt++) {
                #pragma unroll
                for (int r = 0; r < 4; r++) {
                    const float p = __expf(s[nt][r] - mnew);
                    ps += p;
                    pf[nt][r] = (_Float16)p;
                }
            }
            ps += __shfl_xor(ps, 16);
            ps += __shfl_xor(ps, 32);
            lrun[qt] = lrun[qt] * alpha + ps;

            #pragma unroll
            for (int dt = 0; dt < 4; dt++) acc[qt][dt] *= alpha;
            // PV: out^T[d][q] += V^T · P^T   (K=16 f16 MFMA, P from registers)
            #pragma unroll
            for (int kb = 0; kb < 4; kb++)
                #pragma unroll
                for (int dt = 0; dt < 4; dt++)
                    acc[qt][dt] = __builtin_amdgcn_mfma_f32_16x16x16f16(vf[kb][dt], pf[kb], acc[qt][dt], 0, 0, 0);
        }
        __syncthreads();
    }

    // ---- epilogue: transpose via per-wave LDS, coalesced bf16 store ----
    const float inv0 = 1.f / lrun[0], inv1 = 1.f / lrun[1];
    ushort_t* Tw = Tr + wid * (32 * LDV);
    #pragma unroll
    for (int qt = 0; qt < 2; qt++) {
        const float inv = qt ? inv1 : inv0;
        #pragma unroll
        for (int dt = 0; dt < 4; dt++)
            #pragma unroll
            for (int r = 0; r < 4; r++)
                Tw[(qt * 16 + l15) * LDV + dt * 16 + quad * 4 + r] = f32_to_bf16(acc[qt][dt][r] * inv);
    }
    const int row = lane >> 1, hf = lane & 1;
    const ushort_t* src = Tw + row * LDV + hf * 32;
    ushort_t* dst = ctx + ((size_t)(b * SS) + q0 + row) * DMODEL + h * HDIM + hf * 32;
    #pragma unroll
    for (int i = 0; i < 4; i++)
        *(uint4*)(dst + i * 8) = *(const uint4*)(src + i * 8);
}

extern "C" void kernel_launch(void* const* d_in, const int* in_sizes, int n_in,
                              void* d_out, int out_size, void* d_ws, size_t ws_size,
                              hipStream_t stream) {
    (void)in_sizes; (void)n_in; (void)out_size; (void)ws_size;
    const float* query = (const float*)d_in[0];
    const float* key_  = (const float*)d_in[1];
    const float* value = (const float*)d_in[2];
    const float* Wq = (const float*)d_in[3];
    const float* bq = (const float*)d_in[4];
    const float* Wk = (const float*)d_in[5];
    const float* bk = (const float*)d_in[6];
    const float* Wv = (const float*)d_in[7];
    const float* bv = (const float*)d_in[8];
    const float* Wo = (const float*)d_in[9];
    const float* bo = (const float*)d_in[10];
    float* out = (float*)d_out;

    // workspace: exactly 64 MiB (proven available in round 1)
    ushort_t* tmp = (ushort_t*)d_ws;          // A bf16 staging; later ctx
    ushort_t* Qw  = tmp + QKV_ELEMS;          // [B,H,S,HDIM] bf16 (pre-scaled)
    ushort_t* Kw  = Qw + QKV_ELEMS;           // [B,H,S,HDIM] bf16
    ushort_t* Vw  = Kw + QKV_ELEMS;           // [B,H,S,HDIM] f16
    ushort_t* ctx = tmp;                      // [B,S,DMODEL] bf16
    // weight scratch parked in d_out (unused until final GEMM)
    ushort_t* Wqb = (ushort_t*)d_out;
    ushort_t* Wkb = Wqb + 1048576;
    ushort_t* Wvb = Wkb + 1048576;
    ushort_t* Wob = Qw;                       // Q buffer dead after attention

    dim3 blk(256);
    dim3 gg(DMODEL / 128, MM / 128);          // 8 x 64 GEMM blocks

    hipLaunchKernelGGL(convert_w3, dim3(512, 3), blk, 0, stream, Wq, Wk, Wv, Wqb, Wkb, Wvb);

    hipLaunchKernelGGL(convert_bf16, dim3(4096), blk, 0, stream, query, tmp);
    hipLaunchKernelGGL((gemm_bf16<0>), gg, blk, 0, stream, tmp, Wqb, bq, (void*)Qw, 0.125f);
    hipLaunchKernelGGL(convert_bf16, dim3(4096), blk, 0, stream, key_, tmp);
    hipLaunchKernelGGL((gemm_bf16<0>), gg, blk, 0, stream, tmp, Wkb, bk, (void*)Kw, 1.0f);
    hipLaunchKernelGGL(convert_bf16, dim3(4096), blk, 0, stream, value, tmp);
    hipLaunchKernelGGL((gemm_bf16<1>), gg, blk, 0, stream, tmp, Wvb, bv, (void*)Vw, 1.0f);

    hipLaunchKernelGGL(attn_kernel, dim3(SS / 128, BB * NHEADS), blk, 0, stream, Qw, Kw, Vw, ctx);

    hipLaunchKernelGGL(convert_bf16, dim3(512), blk, 0, stream, Wo, Wob);
    hipLaunchKernelGGL((gemm_bf16<2>), gg, blk, 0, stream, ctx, Wob, bo, (void*)out, 1.0f);
}

// Round 5
// 404.847 us; speedup vs baseline: 1.4870x; 1.0716x over previous
//
#include <hip/hip_runtime.h>
#include <stdint.h>

#define DMODEL 1024
#define NHEADS 16
#define HDIM   64
#define BB     4
#define SS     2048
#define MM     (BB*SS)                      // 8192 rows
#define QKV_ELEMS ((size_t)8388608)         // B*S*DMODEL

typedef unsigned short ushort_t;
typedef __bf16    bf16x8  __attribute__((ext_vector_type(8)));
typedef _Float16  half4   __attribute__((ext_vector_type(4)));
typedef _Float16  half2_t __attribute__((ext_vector_type(2)));
typedef float     floatx4 __attribute__((ext_vector_type(4)));

__device__ inline ushort_t f32_to_bf16(float f) {
    union { float f; uint32_t u; } v; v.f = f;
    uint32_t r = v.u + 0x7FFF + ((v.u >> 16) & 1);   // RNE
    return (ushort_t)(r >> 16);
}
__device__ inline ushort_t f32_to_f16u(float f) {
    union { _Float16 h; ushort_t u; } v; v.h = (_Float16)f; return v.u;
}
__device__ inline half2_t pkrtz(float a, float b) {
    return __builtin_bit_cast(half2_t, __builtin_amdgcn_cvt_pkrtz(a, b));
}
__device__ inline void glds16(const void* g, void* l) {
    __builtin_amdgcn_global_load_lds(
        (const __attribute__((address_space(1))) unsigned int*)g,
        (__attribute__((address_space(3))) unsigned int*)l, 16, 0, 0);
}

// ---------------------------------------------------------------------------
// fp32 -> bf16 elementwise convert; each block converts 2048 elements.
// ---------------------------------------------------------------------------
__global__ __launch_bounds__(256) void convert_bf16(const float* __restrict__ in,
                                                    ushort_t* __restrict__ out) {
    size_t i = ((size_t)blockIdx.x * 256 + threadIdx.x) * 8;
    float4 a = *(const float4*)&in[i];
    float4 b = *(const float4*)&in[i + 4];
    ushort_t t[8];
    t[0] = f32_to_bf16(a.x); t[1] = f32_to_bf16(a.y);
    t[2] = f32_to_bf16(a.z); t[3] = f32_to_bf16(a.w);
    t[4] = f32_to_bf16(b.x); t[5] = f32_to_bf16(b.y);
    t[6] = f32_to_bf16(b.z); t[7] = f32_to_bf16(b.w);
    *(uint4*)&out[i] = *(uint4*)t;
}

__global__ __launch_bounds__(256) void convert_w3(
    const float* __restrict__ w0, const float* __restrict__ w1, const float* __restrict__ w2,
    ushort_t* __restrict__ o0, ushort_t* __restrict__ o1, ushort_t* __restrict__ o2) {
    const float* src = (blockIdx.y == 0) ? w0 : (blockIdx.y == 1) ? w1 : w2;
    ushort_t*    dst = (blockIdx.y == 0) ? o0 : (blockIdx.y == 1) ? o1 : o2;
    size_t i = ((size_t)blockIdx.x * 256 + threadIdx.x) * 8;
    float4 a = *(const float4*)&src[i];
    float4 b = *(const float4*)&src[i + 4];
    ushort_t t[8];
    t[0] = f32_to_bf16(a.x); t[1] = f32_to_bf16(a.y);
    t[2] = f32_to_bf16(a.z); t[3] = f32_to_bf16(a.w);
    t[4] = f32_to_bf16(b.x); t[5] = f32_to_bf16(b.y);
    t[6] = f32_to_bf16(b.z); t[7] = f32_to_bf16(b.w);
    *(uint4*)&dst[i] = *(uint4*)t;
}

// ---------------------------------------------------------------------------
// bf16 GEMM, software-pipelined: C[m,n] = (sum_k A[m,k]*W[n,k] + bias)*scale
// Double-buffered LDS, ONE barrier per K-step; glds for tile k+1 issued
// right after the barrier so its latency is hidden by tile-k compute.
// OUT: 0 = bf16 scatter to [B,H,S,HDIM]; 1 = f16 scatter; 2 = fp32 [M,DMODEL]
// ---------------------------------------------------------------------------
template<int OUT>
__global__ __launch_bounds__(256) void gemm_bf16(
    const ushort_t* __restrict__ A, const ushort_t* __restrict__ W,
    const float* __restrict__ bias, void* __restrict__ O, float scale)
{
    __shared__ ushort_t As[2 * 128 * 32];
    __shared__ ushort_t Bs[2 * 128 * 32];

    const int tid  = threadIdx.x;
    const int lane = tid & 63;
    const int quad = lane >> 4;
    const int l15  = lane & 15;
    const int wid  = tid >> 6;
    const int wr   = wid >> 1, wc = wid & 1;
    const int m0   = blockIdx.y * 128;
    const int n0   = blockIdx.x * 128;

    floatx4 acc[4][4];
    #pragma unroll
    for (int i = 0; i < 4; i++)
        #pragma unroll
        for (int j = 0; j < 4; j++)
            acc[i][j] = (floatx4){0.f, 0.f, 0.f, 0.f};

    // prologue: stage K-tile 0 into buffer 0
    #pragma unroll
    for (int j = 0; j < 2; j++) {
        const int p = tid + j * 256, row = p >> 2, cc = p & 3;
        glds16(&A[(size_t)(m0 + row) * DMODEL + cc * 8], &As[p * 8]);
        glds16(&W[(size_t)(n0 + row) * DMODEL + cc * 8], &Bs[p * 8]);
    }

    for (int k0 = 0; k0 < DMODEL; k0 += 32) {
        const int cb = ((k0 >> 5) & 1) * (128 * 32);
        const int nbo = (128 * 32) - cb;
        __syncthreads();                         // buf[cb] ready, other free
        const int kn = (k0 + 32) & (DMODEL - 1); // wraps on last iter (harmless)
        #pragma unroll
        for (int j = 0; j < 2; j++) {
            const int p = tid + j * 256, row = p >> 2, cc = p & 3;
            glds16(&A[(size_t)(m0 + row) * DMODEL + kn + cc * 8], &As[nbo + p * 8]);
            glds16(&W[(size_t)(n0 + row) * DMODEL + kn + cc * 8], &Bs[nbo + p * 8]);
        }
        bf16x8 af[4], bf[4];
        #pragma unroll
        for (int i = 0; i < 4; i++)
            af[i] = *(const bf16x8*)&As[cb + (wr * 64 + i * 16 + l15) * 32 + quad * 8];
        #pragma unroll
        for (int j = 0; j < 4; j++)
            bf[j] = *(const bf16x8*)&Bs[cb + (wc * 64 + j * 16 + l15) * 32 + quad * 8];
        #pragma unroll
        for (int i = 0; i < 4; i++)
            #pragma unroll
            for (int j = 0; j < 4; j++)
                acc[i][j] = __builtin_amdgcn_mfma_f32_16x16x32_bf16(af[i], bf[j], acc[i][j], 0, 0, 0);
    }

    #pragma unroll
    for (int j = 0; j < 4; j++) {
        const int n = n0 + wc * 64 + j * 16 + l15;
        const float bn = bias[n];
        #pragma unroll
        for (int i = 0; i < 4; i++) {
            #pragma unroll
            for (int r = 0; r < 4; r++) {
                const int m = m0 + wr * 64 + i * 16 + quad * 4 + r;
                float v = (acc[i][j][r] + bn) * scale;
                if (OUT == 0) {
                    const int b = m >> 11, s = m & 2047;
                    const int hh = n >> 6, dh = n & 63;
                    ((ushort_t*)O)[(((size_t)(b * NHEADS + hh)) * SS + s) * HDIM + dh] = f32_to_bf16(v);
                } else if (OUT == 1) {
                    const int b = m >> 11, s = m & 2047;
                    const int hh = n >> 6, dh = n & 63;
                    ((ushort_t*)O)[(((size_t)(b * NHEADS + hh)) * SS + s) * HDIM + dh] = f32_to_f16u(v);
                } else {
                    ((float*)O)[(size_t)m * DMODEL + n] = v;
                }
            }
        }
    }
}

// ---------------------------------------------------------------------------
// Flash attention, transposed-score, software-pipelined (1 barrier/tile).
// grid 1024 blocks (XCD-swizzled so a head's 16 q-blocks share an XCD),
// block 256 = 4 waves x 32 q. Scores arrive in log2 domain (0.125*log2e
// folded into Q projection): p = exp2(s-m). P packed via cvt_pkrtz, row-sum
// via v_dot2_f32_f16, PV straight from registers (f16 MFMA, V transposed).
// LDS buffer bases computed by integer offset (no LDS-pointer arrays: the
// gfx950 backend rejects the addrspacecast static initializer they create).
// ---------------------------------------------------------------------------
__global__ __launch_bounds__(256, 4) void attn_kernel(
    const ushort_t* __restrict__ Q, const ushort_t* __restrict__ K,
    const ushort_t* __restrict__ V, ushort_t* __restrict__ ctx)
{
    constexpr int LDV = 72;
    constexpr int VOFF = 2 * 4096;                       // Vt region base
    __shared__ ushort_t smem[2 * 4096 + 2 * 64 * LDV];   // 34.0 KiB
    ushort_t* Tr = smem;                                 // epilogue scratch

    const int tid  = threadIdx.x;
    const int lane = tid & 63;
    const int wid  = tid >> 6;
    const int quad = lane >> 4;
    const int l15  = lane & 15;
    const int bid  = blockIdx.x;
    const int bh   = (bid & 7) * 8 + (bid >> 7);          // same head -> same XCD
    const int b    = bh >> 4, h = bh & 15;
    const int q0   = ((bid >> 3) & 15) * 128 + wid * 32;

    const ushort_t* Qb = Q + (size_t)bh * SS * HDIM;
    const ushort_t* Kb = K + (size_t)bh * SS * HDIM;
    const ushort_t* Vb = V + (size_t)bh * SS * HDIM;

    // Q fragments (B-operand: lane&15 = q, quad*8+j = dim), 2 q-tiles
    bf16x8 qf[2][2];
    #pragma unroll
    for (int qt = 0; qt < 2; qt++)
        #pragma unroll
        for (int c = 0; c < 2; c++)
            qf[qt][c] = *(const bf16x8*)&Qb[(size_t)(q0 + qt * 16 + l15) * HDIM + c * 32 + quad * 8];

    floatx4 acc[2][4];
    #pragma unroll
    for (int qt = 0; qt < 2; qt++)
        #pragma unroll
        for (int dt = 0; dt < 4; dt++)
            acc[qt][dt] = (floatx4){0.f, 0.f, 0.f, 0.f};
    float mrun[2] = {-1e30f, -1e30f};
    float lrun[2] = {0.f, 0.f};

    const int kp = tid & 31;    // key pair for V staging
    const int dc = tid >> 5;    // dim chunk for V staging

    // ---- prologue: stage tile 0 ----
    #pragma unroll
    for (int j = 0; j < 2; j++) {
        const int p = tid + j * 256, row = p >> 3, cc = (p & 7) ^ (row & 7);
        glds16(&Kb[(size_t)row * HDIM + cc * 8], &smem[p * 8]);
    }
    {
        ushort_t ua[8], ub[8];
        *(uint4*)ua = *(const uint4*)&Vb[(size_t)(2 * kp) * HDIM + dc * 8];
        *(uint4*)ub = *(const uint4*)&Vb[(size_t)(2 * kp + 1) * HDIM + dc * 8];
        #pragma unroll
        for (int i = 0; i < 8; i++)
            *(uint32_t*)&smem[VOFF + (dc * 8 + i) * LDV + 2 * kp] = (uint32_t)ua[i] | ((uint32_t)ub[i] << 16);
    }

    const half2_t one2 = {(_Float16)1.f, (_Float16)1.f};

    for (int kt = 0; kt < SS; kt += 64) {
        const int cur = ((kt >> 6) & 1);
        const int ko  = cur * 4096;                  // current K buf offset
        const int kon = 4096 - ko;                   // next K buf offset
        const int vo  = VOFF + cur * (64 * LDV);     // current Vt buf offset
        const int von = VOFF + (64 * LDV) - cur * (64 * LDV);
        __syncthreads();   // tile(kt) staged; other buffers free

        // ---- prefetch tile kt+64 (wraps on last iter; harmless) ----
        const int ktn = (kt + 64) & (SS - 1);
        #pragma unroll
        for (int j = 0; j < 2; j++) {
            const int p = tid + j * 256, row = p >> 3, cc = (p & 7) ^ (row & 7);
            glds16(&Kb[(size_t)(ktn + row) * HDIM + cc * 8], &smem[kon + p * 8]);
        }
        ushort_t ua[8], ub[8];
        *(uint4*)ua = *(const uint4*)&Vb[(size_t)(ktn + 2 * kp) * HDIM + dc * 8];
        *(uint4*)ub = *(const uint4*)&Vb[(size_t)(ktn + 2 * kp + 1) * HDIM + dc * 8];

        // ---- fragments for tile kt ----
        bf16x8 kf[4][2];
        #pragma unroll
        for (int nt = 0; nt < 4; nt++) {
            const int row = nt * 16 + l15;
            #pragma unroll
            for (int c = 0; c < 2; c++) {
                const int pos = (c * 4 + quad) ^ (row & 7);
                kf[nt][c] = *(const bf16x8*)&smem[ko + row * 64 + pos * 8];
            }
        }
        half4 vf[4][4];
        #pragma unroll
        for (int kb = 0; kb < 4; kb++)
            #pragma unroll
            for (int dt = 0; dt < 4; dt++)
                vf[kb][dt] = *(const half4*)&smem[vo + (dt * 16 + l15) * LDV + kb * 16 + quad * 4];

        #pragma unroll
        for (int qt = 0; qt < 2; qt++) {
            // S^T[key][q] in log2 domain
            floatx4 s[4];
            #pragma unroll
            for (int nt = 0; nt < 4; nt++) {
                floatx4 cz = (floatx4){0.f, 0.f, 0.f, 0.f};
                cz = __builtin_amdgcn_mfma_f32_16x16x32_bf16(kf[nt][0], qf[qt][0], cz, 0, 0, 0);
                cz = __builtin_amdgcn_mfma_f32_16x16x32_bf16(kf[nt][1], qf[qt][1], cz, 0, 0, 0);
                s[nt] = cz;
            }
            float mx = s[0][0];
            #pragma unroll
            for (int nt = 0; nt < 4; nt++)
                #pragma unroll
                for (int r = 0; r < 4; r++) mx = fmaxf(mx, s[nt][r]);
            mx = fmaxf(mx, __shfl_xor(mx, 16));
            mx = fmaxf(mx, __shfl_xor(mx, 32));
            const float mnew  = fmaxf(mrun[qt], mx);
            const float alpha = __builtin_amdgcn_exp2f(mrun[qt] - mnew);
            mrun[qt] = mnew;

            float ps = 0.f;
            half4 pf[4];
            #pragma unroll
            for (int nt = 0; nt < 4; nt++) {
                const float p0 = __builtin_amdgcn_exp2f(s[nt][0] - mnew);
                const float p1 = __builtin_amdgcn_exp2f(s[nt][1] - mnew);
                const float p2 = __builtin_amdgcn_exp2f(s[nt][2] - mnew);
                const float p3 = __builtin_amdgcn_exp2f(s[nt][3] - mnew);
                const half2_t ha = pkrtz(p0, p1);
                const half2_t hb = pkrtz(p2, p3);
                ps = __builtin_amdgcn_fdot2(ha, one2, ps, false);
                ps = __builtin_amdgcn_fdot2(hb, one2, ps, false);
                union { half4 h4; half2_t h2[2]; } u;
                u.h2[0] = ha; u.h2[1] = hb;
                pf[nt] = u.h4;
            }
            ps += __shfl_xor(ps, 16);
            ps += __shfl_xor(ps, 32);
            lrun[qt] = lrun[qt] * alpha + ps;

            #pragma unroll
            for (int dt = 0; dt < 4; dt++) acc[qt][dt] *= alpha;
            #pragma unroll
            for (int kb = 0; kb < 4; kb++)
                #pragma unroll
                for (int dt = 0; dt < 4; dt++)
                    acc[qt][dt] = __builtin_amdgcn_mfma_f32_16x16x16f16(vf[kb][dt], pf[kb], acc[qt][dt], 0, 0, 0);
        }

        // ---- write prefetched V into the spare buffer ----
        #pragma unroll
        for (int i = 0; i < 8; i++)
            *(uint32_t*)&smem[von + (dc * 8 + i) * LDV + 2 * kp] = (uint32_t)ua[i] | ((uint32_t)ub[i] << 16);
    }

    // ---- epilogue: per-wave LDS transpose, coalesced bf16 store ----
    __syncthreads();
    const float inv0 = 1.f / lrun[0], inv1 = 1.f / lrun[1];
    ushort_t* Tw = Tr + wid * (32 * LDV);
    #pragma unroll
    for (int qt = 0; qt < 2; qt++) {
        const float inv = qt ? inv1 : inv0;
        #pragma unroll
        for (int dt = 0; dt < 4; dt++)
            #pragma unroll
            for (int r = 0; r < 4; r++)
                Tw[(qt * 16 + l15) * LDV + dt * 16 + quad * 4 + r] = f32_to_bf16(acc[qt][dt][r] * inv);
    }
    const int row = lane >> 1, hf = lane & 1;
    const ushort_t* src = Tw + row * LDV + hf * 32;
    ushort_t* dst = ctx + ((size_t)(b * SS) + q0 + row) * DMODEL + h * HDIM + hf * 32;
    #pragma unroll
    for (int i = 0; i < 4; i++)
        *(uint4*)(dst + i * 8) = *(const uint4*)(src + i * 8);
}

extern "C" void kernel_launch(void* const* d_in, const int* in_sizes, int n_in,
                              void* d_out, int out_size, void* d_ws, size_t ws_size,
                              hipStream_t stream) {
    (void)in_sizes; (void)n_in; (void)out_size; (void)ws_size;
    const float* query = (const float*)d_in[0];
    const float* key_  = (const float*)d_in[1];
    const float* value = (const float*)d_in[2];
    const float* Wq = (const float*)d_in[3];
    const float* bq = (const float*)d_in[4];
    const float* Wk = (const float*)d_in[5];
    const float* bk = (const float*)d_in[6];
    const float* Wv = (const float*)d_in[7];
    const float* bv = (const float*)d_in[8];
    const float* Wo = (const float*)d_in[9];
    const float* bo = (const float*)d_in[10];
    float* out = (float*)d_out;

    // workspace: 64 MiB
    ushort_t* tmp = (ushort_t*)d_ws;          // A bf16 staging; later ctx
    ushort_t* Qw  = tmp + QKV_ELEMS;          // [B,H,S,HDIM] bf16 (log2-scaled)
    ushort_t* Kw  = Qw + QKV_ELEMS;           // [B,H,S,HDIM] bf16
    ushort_t* Vw  = Kw + QKV_ELEMS;           // [B,H,S,HDIM] f16
    ushort_t* ctx = tmp;                      // [B,S,DMODEL] bf16
    // weight scratch parked in d_out (dead until final GEMM)
    ushort_t* Wqb = (ushort_t*)d_out;
    ushort_t* Wkb = Wqb + 1048576;
    ushort_t* Wvb = Wkb + 1048576;
    ushort_t* Wob = Qw;                       // Q buffer dead after attention

    dim3 blk(256);
    dim3 gg(DMODEL / 128, MM / 128);

    hipLaunchKernelGGL(convert_w3, dim3(512, 3), blk, 0, stream, Wq, Wk, Wv, Wqb, Wkb, Wvb);

    // Q scale = (1/sqrt(64)) * log2(e): scores exit QK^T in log2 domain
    hipLaunchKernelGGL(convert_bf16, dim3(4096), blk, 0, stream, query, tmp);
    hipLaunchKernelGGL((gemm_bf16<0>), gg, blk, 0, stream, tmp, Wqb, bq, (void*)Qw, 0.18033688011f);
    hipLaunchKernelGGL(convert_bf16, dim3(4096), blk, 0, stream, key_, tmp);
    hipLaunchKernelGGL((gemm_bf16<0>), gg, blk, 0, stream, tmp, Wkb, bk, (void*)Kw, 1.0f);
    hipLaunchKernelGGL(convert_bf16, dim3(4096), blk, 0, stream, value, tmp);
    hipLaunchKernelGGL((gemm_bf16<1>), gg, blk, 0, stream, tmp, Wvb, bv, (void*)Vw, 1.0f);

    hipLaunchKernelGGL(attn_kernel, dim3(1024), blk, 0, stream, Qw, Kw, Vw, ctx);

    hipLaunchKernelGGL(convert_bf16, dim3(512), blk, 0, stream, Wo, Wob);
    hipLaunchKernelGGL((gemm_bf16<2>), gg, blk, 0, stream, ctx, Wob, bo, (void*)out, 1.0f);
}